// Round 10
// baseline (481.789 us; speedup 1.0000x reference)
//
#include <hip/hip_runtime.h>

typedef unsigned int u32;
typedef unsigned short u16;
typedef __attribute__((ext_vector_type(8))) short short8;   // 8 x bf16 (guide-verified frag type)
typedef __attribute__((ext_vector_type(4))) float f32x4;

__device__ __forceinline__ u16 f2bf(float f) {
    u32 u = __float_as_uint(f);
    u32 r = (u + 0x7fffu + ((u >> 16) & 1u)) >> 16;   // RNE
    return (u16)r;
}
__device__ __forceinline__ float bf2f(u32 lo16) { return __uint_as_float(lo16 << 16); }

__device__ __forceinline__ void acc_u4(float* a, uint4 v) {
    a[0] += bf2f(v.x & 0xffffu); a[1] += bf2f(v.x >> 16);
    a[2] += bf2f(v.y & 0xffffu); a[3] += bf2f(v.y >> 16);
    a[4] += bf2f(v.z & 0xffffu); a[5] += bf2f(v.z >> 16);
    a[6] += bf2f(v.w & 0xffffu); a[7] += bf2f(v.w >> 16);
}

// ---------------- prep ----------------

// fused transposed weights for all 3 layers in one launch
__global__ __launch_bounds__(256) void prep_w_all(const float* __restrict__ ws0, const float* __restrict__ wn0, u16* __restrict__ wt0,
                                                  const float* __restrict__ ws1, const float* __restrict__ wn1, u16* __restrict__ wt1,
                                                  const float* __restrict__ ws2, const float* __restrict__ wn2, u16* __restrict__ wt2) {
    int bid = blockIdx.x;
    const float *ws, *wn;
    u16* wt;
    int dout, HW, local;
    if (bid < 128)      { ws = ws0; wn = wn0; wt = wt0; dout = 128; HW = 128; local = bid; }
    else if (bid < 256) { ws = ws1; wn = wn1; wt = wt1; dout = 128; HW = 128; local = bid - 128; }
    else                { ws = ws2; wn = wn2; wt = wt2; dout = 47;  HW = 64;  local = bid - 256; }
    int idx = local * 256 + threadIdx.x;   // idx = n*128 + k
    int n = idx >> 7, k = idx & 127;
    float v = 0.f;
    if (n < HW) { if (n < dout) v = ws[k * dout + n]; }
    else { int nn = n - HW; if (nn < dout) v = wn[k * dout + nn]; }
    wt[idx] = f2bf(v);
}

// ---------------- CSR build ----------------

__global__ __launch_bounds__(256) void hist_k(const int* __restrict__ dst,
                                              int* __restrict__ deg, int E) {
    int i = blockIdx.x * 256 + threadIdx.x;
    if (i < E) atomicAdd(&deg[dst[i]], 1);
}

__global__ __launch_bounds__(256) void scan_partial(const int* __restrict__ deg,
                                                    int* __restrict__ bsum, int Nn) {
    __shared__ int sm[256];
    int t = threadIdx.x;
    int base = blockIdx.x * 1024 + t * 4;
    int s = 0;
#pragma unroll
    for (int j = 0; j < 4; j++)
        if (base + j < Nn) s += deg[base + j];
    sm[t] = s;
    __syncthreads();
    for (int off = 128; off > 0; off >>= 1) {
        if (t < off) sm[t] += sm[t + off];
        __syncthreads();
    }
    if (t == 0) bsum[blockIdx.x] = sm[0];
}

__global__ __launch_bounds__(256) void scan_offsets(const int* __restrict__ bsum,
                                                    int* __restrict__ boff, int nb) {
    __shared__ int sm[256];
    int t = threadIdx.x;
    int v = (t < nb) ? bsum[t] : 0;
    sm[t] = v;
    __syncthreads();
    for (int off = 1; off < 256; off <<= 1) {
        int u = (t >= off) ? sm[t - off] : 0;
        __syncthreads();
        sm[t] += u;
        __syncthreads();
    }
    if (t < nb) boff[t] = sm[t] - v;
}

// rowptr + invd + bucket cursor init (cursor[b] = rowptr[b*512])
__global__ __launch_bounds__(1024) void scan_final(const int* __restrict__ deg,
                                                   const int* __restrict__ boff,
                                                   int* __restrict__ rowptr,
                                                   float* __restrict__ invd,
                                                   int* __restrict__ cursor,
                                                   int Nn, int E) {
    __shared__ int sm[1024];
    int t = threadIdx.x;
    int i = blockIdx.x * 1024 + t;
    int v = (i < Nn) ? deg[i] : 0;
    sm[t] = v;
    __syncthreads();
    for (int off = 1; off < 1024; off <<= 1) {
        int u = (t >= off) ? sm[t - off] : 0;
        __syncthreads();
        sm[t] += u;
        __syncthreads();
    }
    if (i < Nn) {
        int rp = boff[blockIdx.x] + sm[t] - v;   // exclusive
        rowptr[i] = rp;
        invd[i] = 1.0f / (float)max(v, 1);
        if ((i & 511) == 0) cursor[i >> 9] = rp;
    }
    if (i == Nn) rowptr[Nn] = E;
}

// multisplit pass 1: tile -> LDS bucket-compaction -> contiguous bucket segments
#define TILE 4096
__global__ __launch_bounds__(512) void bucket_scatter(const int* __restrict__ src,
                                                      const int* __restrict__ dst,
                                                      int* __restrict__ cursor,
                                                      uint2* __restrict__ pairs, int E) {
    __shared__ uint2 sp[TILE];                         // 32 KB
    __shared__ int s_cnt[256], s_off[256], s_gpos[256], s_cnt2[256];
    const int tid = threadIdx.x;
    const int base = blockIdx.x * TILE;
    const int tn = min(TILE, E - base);
    if (tid < 256) { s_cnt[tid] = 0; s_cnt2[tid] = 0; }
    __syncthreads();
    int d[8], s[8];
#pragma unroll
    for (int j = 0; j < 8; j++) {
        int k = tid + j * 512;
        if (k < tn) {
            d[j] = dst[base + k];
            s[j] = src[base + k];
            atomicAdd(&s_cnt[d[j] >> 9], 1);
        } else d[j] = -1;
    }
    __syncthreads();
    if (tid < 256) s_off[tid] = s_cnt[tid];
    __syncthreads();
    for (int off = 1; off < 256; off <<= 1) {
        int v = 0;
        if (tid < 256 && tid >= off) v = s_off[tid - off];
        __syncthreads();
        if (tid < 256) s_off[tid] += v;
        __syncthreads();
    }
    if (tid < 256 && s_cnt[tid] > 0) s_gpos[tid] = atomicAdd(&cursor[tid], s_cnt[tid]);
    __syncthreads();
#pragma unroll
    for (int j = 0; j < 8; j++) {
        if (d[j] >= 0) {
            int b = d[j] >> 9;
            int p = atomicAdd(&s_cnt2[b], 1);
            sp[s_off[b] - s_cnt[b] + p] = make_uint2((u32)d[j], (u32)s[j]);
        }
    }
    __syncthreads();
    for (int k = tid; k < tn; k += 512) {
        uint2 pr = sp[k];
        int b = (int)(pr.x >> 9);
        pairs[s_gpos[b] + (k - (s_off[b] - s_cnt[b]))] = pr;
    }
}

// multisplit pass 2: per-bucket exact CSR placement via LDS counters, coalesced writeback
#define LDSCAP 12288
__global__ __launch_bounds__(512) void build_csr(const uint2* __restrict__ pairs,
                                                 const int* __restrict__ rowptr,
                                                 int* __restrict__ cols, int Nn) {
    __shared__ int s_cols[LDSCAP];                     // 48 KB
    __shared__ int s_row[513];
    __shared__ int s_cnt[512];
    const int tid = threadIdx.x;
    const int d0 = blockIdx.x * 512;
    const int nd = min(512, Nn - d0);
    for (int i = tid; i <= nd; i += 512) s_row[i] = rowptr[d0 + i];
    if (tid < nd) s_cnt[tid] = 0;
    __syncthreads();
    const int base = s_row[0];
    const int n = s_row[nd] - base;
    const bool fit = (n <= LDSCAP);
    for (int k = tid; k < n; k += 512) {
        uint2 pr = pairs[base + k];
        int dl = (int)pr.x - d0;
        int p = atomicAdd(&s_cnt[dl], 1);
        int pos = s_row[dl] - base + p;
        if (fit) s_cols[pos] = (int)pr.y;
        else cols[base + pos] = (int)pr.y;             // overflow fallback (never expected)
    }
    __syncthreads();
    if (fit)
        for (int k = tid; k < n; k += 512) cols[base + k] = s_cols[k];
}

// ---------------- layer-0 GEMM (LDS-staged, fp32 A with fused convert) ----------------
#define KDIM 128
#define KP 136

__global__ __launch_bounds__(256) void gemm_l0(const float* __restrict__ Af,
                                               const u16* __restrict__ Bt,
                                               u16* __restrict__ C, int M) {
    __shared__ u16 As[64 * KP];
    __shared__ u16 Bs[128 * KP];
    const int row0 = blockIdx.x * 64;
    const int col0 = blockIdx.y * 128;
    const int tid = threadIdx.x;

#pragma unroll
    for (int i = 0; i < 4; i++) {
        int idx = tid + i * 256;
        int r = idx >> 4, c = idx & 15;
        uint4 v = make_uint4(0, 0, 0, 0);
        if (row0 + r < M) {
            const float4* rowp = (const float4*)(Af + (size_t)(row0 + r) * KDIM);
            float4 f0 = rowp[2 * c];
            float4 f1 = rowp[2 * c + 1];
            v.x = (u32)f2bf(f0.x) | ((u32)f2bf(f0.y) << 16);
            v.y = (u32)f2bf(f0.z) | ((u32)f2bf(f0.w) << 16);
            v.z = (u32)f2bf(f1.x) | ((u32)f2bf(f1.y) << 16);
            v.w = (u32)f2bf(f1.z) | ((u32)f2bf(f1.w) << 16);
        }
        ((uint4*)(As + r * KP))[c] = v;
    }
#pragma unroll
    for (int i = 0; i < 8; i++) {
        int idx = tid + i * 256;
        int r = idx >> 4, c = idx & 15;
        uint4 v = ((const uint4*)(Bt + (size_t)(col0 + r) * KDIM))[c];
        ((uint4*)(Bs + r * KP))[c] = v;
    }
    __syncthreads();

    const int lane = tid & 63, wave = tid >> 6;
    const int quad = lane >> 4, l16 = lane & 15;
    const int wcol = wave * 32;

    f32x4 acc[4][2];
#pragma unroll
    for (int mt = 0; mt < 4; mt++)
#pragma unroll
        for (int nt = 0; nt < 2; nt++) acc[mt][nt] = (f32x4){0.f, 0.f, 0.f, 0.f};

#pragma unroll
    for (int kc = 0; kc < 4; kc++) {
        short8 a[4], b[2];
#pragma unroll
        for (int mt = 0; mt < 4; mt++)
            a[mt] = *(const short8*)(As + (size_t)(mt * 16 + l16) * KP + kc * 32 + quad * 8);
#pragma unroll
        for (int nt = 0; nt < 2; nt++)
            b[nt] = *(const short8*)(Bs + (size_t)(wcol + nt * 16 + l16) * KP + kc * 32 + quad * 8);
#pragma unroll
        for (int mt = 0; mt < 4; mt++)
#pragma unroll
            for (int nt = 0; nt < 2; nt++)
                acc[mt][nt] = __builtin_amdgcn_mfma_f32_16x16x32_bf16(a[mt], b[nt], acc[mt][nt], 0, 0, 0);
    }

    // C/D layout: col = lane&15, row = quad*4 + reg   [verified m89/m91]
#pragma unroll
    for (int mt = 0; mt < 4; mt++) {
#pragma unroll
        for (int i = 0; i < 4; i++) {
            int r = row0 + mt * 16 + quad * 4 + i;
            if (r < M) {
#pragma unroll
                for (int nt = 0; nt < 2; nt++)
                    C[(size_t)r * 256 + (col0 + wcol + nt * 16 + l16)] = f2bf(acc[mt][nt][i]);
            }
        }
    }
}

// ---------------- LDS-free GEMM (layers 1,2): fragments straight from L1/L2 ----------------
// K=128 makes LDS staging unamortizable; A tile (16 KB) is L1-resident across the
// block's 4 waves, B (<=64 KB) is L2-hot. Zero barriers, zero LDS -> high occupancy.
// Tail block: A-row index clamped to M-1; the polluted acc rows are >= M, never stored.
template <int NCOLS>
__global__ __launch_bounds__(256) void gemm_nolds(const u16* __restrict__ A,
                                                  const u16* __restrict__ Bt,
                                                  u16* __restrict__ C, int M) {
    const int row0 = blockIdx.x * 64;
    const int col0 = blockIdx.y * 128;
    const int lane = threadIdx.x & 63, wave = threadIdx.x >> 6;
    const int quad = lane >> 4, l16 = lane & 15;
    const int wcol = wave * 32;

    f32x4 acc[4][2];
#pragma unroll
    for (int mt = 0; mt < 4; mt++)
#pragma unroll
        for (int nt = 0; nt < 2; nt++) acc[mt][nt] = (f32x4){0.f, 0.f, 0.f, 0.f};

    const u16* arow[4];
#pragma unroll
    for (int mt = 0; mt < 4; mt++) {
        int r = min(row0 + mt * 16 + l16, M - 1);
        arow[mt] = A + (size_t)r * KDIM;
    }
    const u16* brow[2];
#pragma unroll
    for (int nt = 0; nt < 2; nt++)
        brow[nt] = Bt + (size_t)(col0 + wcol + nt * 16 + l16) * KDIM;

#pragma unroll
    for (int kc = 0; kc < 4; kc++) {
        short8 a[4], b[2];
#pragma unroll
        for (int mt = 0; mt < 4; mt++)
            a[mt] = *(const short8*)(arow[mt] + kc * 32 + quad * 8);
#pragma unroll
        for (int nt = 0; nt < 2; nt++)
            b[nt] = *(const short8*)(brow[nt] + kc * 32 + quad * 8);
#pragma unroll
        for (int mt = 0; mt < 4; mt++)
#pragma unroll
            for (int nt = 0; nt < 2; nt++)
                acc[mt][nt] = __builtin_amdgcn_mfma_f32_16x16x32_bf16(a[mt], b[nt], acc[mt][nt], 0, 0, 0);
    }

#pragma unroll
    for (int mt = 0; mt < 4; mt++) {
#pragma unroll
        for (int i = 0; i < 4; i++) {
            int r = row0 + mt * 16 + quad * 4 + i;
            if (r < M) {
#pragma unroll
                for (int nt = 0; nt < 2; nt++)
                    C[(size_t)r * NCOLS + (col0 + wcol + nt * 16 + l16)] = f2bf(acc[mt][nt][i]);
            }
        }
    }
}

// ---------------- 128-col aggregation: 2 nodes/wave, 4 gathers in flight ----------------
// out2 = [M][256] bf16 (s | t).  outp = [M][128] bf16.
template <bool RELU>
__global__ __launch_bounds__(256) void agg128_k(const u16* __restrict__ out2,
                                                const int* __restrict__ rowptr,
                                                const int* __restrict__ cols,
                                                const float* __restrict__ invd,
                                                const float* __restrict__ bias,
                                                u16* __restrict__ outp, int Mn) {
    int wave = threadIdx.x >> 6, lane = threadIdx.x & 63;
    int nA = blockIdx.x * 8 + wave * 2;
    if (nA >= Mn) return;
    const int nB = nA + 1;
    const bool hasB = (nB < Mn);
    int sub = lane >> 4, l16 = lane & 15;               // 4 slots x 16 lanes
    const u16* tb = out2 + 128 + 8 * l16;
    int begA = rowptr[nA], endA = rowptr[nA + 1];
    int begB = 0, endB = 0;
    if (hasB) { begB = rowptr[nB]; endB = rowptr[nB + 1]; }
    float aA[8] = {0.f, 0.f, 0.f, 0.f, 0.f, 0.f, 0.f, 0.f};
    float aB[8] = {0.f, 0.f, 0.f, 0.f, 0.f, 0.f, 0.f, 0.f};
    int eA = begA + sub, eB = begB + sub;
    while (eA < endA || eB < endB) {
        bool pA0 = eA < endA, pA1 = eA + 4 < endA;
        bool pB0 = eB < endB, pB1 = eB + 4 < endB;
        int sA0 = pA0 ? cols[eA] : 0;
        int sA1 = pA1 ? cols[eA + 4] : 0;
        int sB0 = pB0 ? cols[eB] : 0;
        int sB1 = pB1 ? cols[eB + 4] : 0;
        uint4 vA0 = *(const uint4*)(tb + (size_t)sA0 * 256);
        uint4 vA1 = *(const uint4*)(tb + (size_t)sA1 * 256);
        uint4 vB0 = *(const uint4*)(tb + (size_t)sB0 * 256);
        uint4 vB1 = *(const uint4*)(tb + (size_t)sB1 * 256);
        if (!pA0) vA0 = make_uint4(0, 0, 0, 0);
        if (!pA1) vA1 = make_uint4(0, 0, 0, 0);
        if (!pB0) vB0 = make_uint4(0, 0, 0, 0);
        if (!pB1) vB1 = make_uint4(0, 0, 0, 0);
        acc_u4(aA, vA0); acc_u4(aA, vA1);
        acc_u4(aB, vB0); acc_u4(aB, vB1);
        eA += 8; eB += 8;
    }
#pragma unroll
    for (int j = 0; j < 8; j++) {                       // reduce across 4 slots
        aA[j] += __shfl_xor(aA[j], 16); aA[j] += __shfl_xor(aA[j], 32);
        aB[j] += __shfl_xor(aB[j], 16); aB[j] += __shfl_xor(aB[j], 32);
    }
    if (sub == 0 || (sub == 1 && hasB)) {               // sub0 -> nA, sub1 -> nB (parallel epilogues)
        int node = (sub == 0) ? nA : nB;
        float o[8];
#pragma unroll
        for (int j = 0; j < 8; j++) o[j] = (sub == 0) ? aA[j] : aB[j];
        float id = invd[node];
        uint4 sv = *(const uint4*)(out2 + (size_t)node * 256 + 8 * l16);
        float4 b0 = *(const float4*)(bias + 8 * l16);
        float4 b1 = *(const float4*)(bias + 8 * l16 + 4);
        float o0 = bf2f(sv.x & 0xffffu) + o[0] * id + b0.x;
        float o1 = bf2f(sv.x >> 16)     + o[1] * id + b0.y;
        float o2 = bf2f(sv.y & 0xffffu) + o[2] * id + b0.z;
        float o3 = bf2f(sv.y >> 16)     + o[3] * id + b0.w;
        float o4 = bf2f(sv.z & 0xffffu) + o[4] * id + b1.x;
        float o5 = bf2f(sv.z >> 16)     + o[5] * id + b1.y;
        float o6 = bf2f(sv.w & 0xffffu) + o[6] * id + b1.z;
        float o7 = bf2f(sv.w >> 16)     + o[7] * id + b1.w;
        if (RELU) {
            o0 = fmaxf(o0, 0.f); o1 = fmaxf(o1, 0.f); o2 = fmaxf(o2, 0.f); o3 = fmaxf(o3, 0.f);
            o4 = fmaxf(o4, 0.f); o5 = fmaxf(o5, 0.f); o6 = fmaxf(o6, 0.f); o7 = fmaxf(o7, 0.f);
        }
        uint4 w;
        w.x = (u32)f2bf(o0) | ((u32)f2bf(o1) << 16);
        w.y = (u32)f2bf(o2) | ((u32)f2bf(o3) << 16);
        w.z = (u32)f2bf(o4) | ((u32)f2bf(o5) << 16);
        w.w = (u32)f2bf(o6) | ((u32)f2bf(o7) << 16);
        *(uint4*)(outp + (size_t)node * 128 + 8 * l16) = w;
    }
}

// ---------------- layer-2 aggregation: 2 nodes/wave, 4 gathers in flight, fp32 out ----------------
// out2 = [M][128] bf16: s at cols 0..63 (live 0..46), t at cols 64..127 (live 64..110).
__global__ __launch_bounds__(256) void agg_out8_k(const u16* __restrict__ out2,
                                                  const int* __restrict__ rowptr,
                                                  const int* __restrict__ cols,
                                                  const float* __restrict__ invd,
                                                  const float* __restrict__ bias,
                                                  float* __restrict__ outp, int Mn) {
    int wave = threadIdx.x >> 6, lane = threadIdx.x & 63;
    int nA = blockIdx.x * 8 + wave * 2;
    if (nA >= Mn) return;
    const int nB = nA + 1;
    const bool hasB = (nB < Mn);
    int e8 = lane >> 3, l8 = lane & 7;                  // 8 slots x 8 lanes
    const u16* tb = out2 + 64 + 8 * l8;
    int begA = rowptr[nA], endA = rowptr[nA + 1];
    int begB = 0, endB = 0;
    if (hasB) { begB = rowptr[nB]; endB = rowptr[nB + 1]; }
    float aA[8] = {0.f, 0.f, 0.f, 0.f, 0.f, 0.f, 0.f, 0.f};
    float aB[8] = {0.f, 0.f, 0.f, 0.f, 0.f, 0.f, 0.f, 0.f};
    int eA = begA + e8, eB = begB + e8;
    while (eA < endA || eB < endB) {
        bool pA0 = eA < endA, pA1 = eA + 8 < endA;
        bool pB0 = eB < endB, pB1 = eB + 8 < endB;
        int sA0 = pA0 ? cols[eA] : 0;
        int sA1 = pA1 ? cols[eA + 8] : 0;
        int sB0 = pB0 ? cols[eB] : 0;
        int sB1 = pB1 ? cols[eB + 8] : 0;
        uint4 vA0 = *(const uint4*)(tb + (size_t)sA0 * 128);
        uint4 vA1 = *(const uint4*)(tb + (size_t)sA1 * 128);
        uint4 vB0 = *(const uint4*)(tb + (size_t)sB0 * 128);
        uint4 vB1 = *(const uint4*)(tb + (size_t)sB1 * 128);
        if (!pA0) vA0 = make_uint4(0, 0, 0, 0);
        if (!pA1) vA1 = make_uint4(0, 0, 0, 0);
        if (!pB0) vB0 = make_uint4(0, 0, 0, 0);
        if (!pB1) vB1 = make_uint4(0, 0, 0, 0);
        acc_u4(aA, vA0); acc_u4(aA, vA1);
        acc_u4(aB, vB0); acc_u4(aB, vB1);
        eA += 16; eB += 16;
    }
#pragma unroll
    for (int j = 0; j < 8; j++) {                       // reduce across 8 slots
        aA[j] += __shfl_xor(aA[j], 8); aA[j] += __shfl_xor(aA[j], 16); aA[j] += __shfl_xor(aA[j], 32);
        aB[j] += __shfl_xor(aB[j], 8); aB[j] += __shfl_xor(aB[j], 16); aB[j] += __shfl_xor(aB[j], 32);
    }
    if (e8 == 0 || (e8 == 1 && hasB)) {                 // e8==0 -> nA, e8==1 -> nB
        int node = (e8 == 0) ? nA : nB;
        float o[8];
#pragma unroll
        for (int j = 0; j < 8; j++) o[j] = (e8 == 0) ? aA[j] : aB[j];
        float id = invd[node];
        uint4 sv = *(const uint4*)(out2 + (size_t)node * 128 + 8 * l8);
        u32 sw[4] = {sv.x, sv.y, sv.z, sv.w};
        float* orow = outp + (size_t)node * 47;
#pragma unroll
        for (int j = 0; j < 8; j++) {
            int c = 8 * l8 + j;
            if (c < 47) {
                float s = bf2f((j & 1) ? (sw[j >> 1] >> 16) : (sw[j >> 1] & 0xffffu));
                orow[c] = s + o[j] * id + bias[c];
            }
        }
    }
}

// ---------------- launch ----------------

extern "C" void kernel_launch(void* const* d_in, const int* in_sizes, int n_in,
                              void* d_out, int out_size, void* d_ws, size_t ws_size,
                              hipStream_t stream) {
    const float* x   = (const float*)d_in[0];
    const int*   src = (const int*)d_in[1];
    const int*   dst = (const int*)d_in[2];
    const float* ws0 = (const float*)d_in[3];
    const float* wn0 = (const float*)d_in[4];
    const float* b0  = (const float*)d_in[5];
    const float* ws1 = (const float*)d_in[6];
    const float* wn1 = (const float*)d_in[7];
    const float* b1  = (const float*)d_in[8];
    const float* ws2 = (const float*)d_in[9];
    const float* wn2 = (const float*)d_in[10];
    const float* b2  = (const float*)d_in[11];

    const int Nn = in_sizes[0] / 128;   // 100000
    const int E  = in_sizes[1];         // 1600000

    char* p = (char*)d_ws;
    auto alloc = [&](size_t bytes) -> void* {
        void* r = (void*)p;
        p += (bytes + 255) & ~(size_t)255;
        return r;
    };
    u16*   bufA   = (u16*)alloc((size_t)Nn * 128 * 2);   // h1 / h2
    u16*   out2   = (u16*)alloc((size_t)Nn * 256 * 2);   // [s|t] per layer; ALSO overlaid as pairs buf
    u16*   wt0    = (u16*)alloc(256 * 128 * 2);
    u16*   wt1    = (u16*)alloc(256 * 128 * 2);
    u16*   wt2    = (u16*)alloc(128 * 128 * 2);
    int*   deg    = (int*)alloc((size_t)Nn * 4);
    int*   rowptr = (int*)alloc((size_t)(Nn + 1) * 4);
    float* invd   = (float*)alloc((size_t)Nn * 4);
    int*   cols   = (int*)alloc((size_t)E * 4);
    int*   bsum   = (int*)alloc(256 * 4);
    int*   boff   = (int*)alloc(256 * 4);
    int*   cursor = (int*)alloc(256 * 4);
    uint2* pairs  = (uint2*)out2;                        // overlay: out2 unused until gemm layer 0

    hipMemsetAsync(deg, 0, (size_t)Nn * 4, stream);

    prep_w_all<<<320, 256, 0, stream>>>(ws0, wn0, wt0, ws1, wn1, wt1, ws2, wn2, wt2);

    hist_k<<<(E + 255) / 256, 256, 0, stream>>>(dst, deg, E);
    const int nb = (Nn + 1023) / 1024;
    const int nb2 = (Nn + 1 + 1023) / 1024;
    scan_partial<<<nb, 256, 0, stream>>>(deg, bsum, Nn);
    scan_offsets<<<1, 256, 0, stream>>>(bsum, boff, nb);
    scan_final<<<nb2, 1024, 0, stream>>>(deg, boff, rowptr, invd, cursor, Nn, E);

    bucket_scatter<<<(E + TILE - 1) / TILE, 512, 0, stream>>>(src, dst, cursor, pairs, E);
    build_csr<<<(Nn + 511) / 512, 512, 0, stream>>>(pairs, rowptr, cols, Nn);

    dim3 ggrid((Nn + 63) / 64, 2);
    dim3 ggrid1((Nn + 63) / 64, 1);
    const int aggGrid = (Nn + 7) / 8;                    // 4 waves x 2 nodes = 8 nodes/block
    // layer 0: LDS-staged GEMM reads x fp32 directly (cvt fused into staging)
    gemm_l0<<<ggrid, 256, 0, stream>>>(x, wt0, out2, Nn);
    agg128_k<true><<<aggGrid, 256, 0, stream>>>(out2, rowptr, cols, invd, b0, bufA, Nn);
    // layer 1: LDS-free GEMM (A bf16, L1-resident tiles)
    gemm_nolds<256><<<ggrid, 256, 0, stream>>>(bufA, wt1, out2, Nn);
    agg128_k<true><<<aggGrid, 256, 0, stream>>>(out2, rowptr, cols, invd, b1, bufA, Nn);
    // layer 2: N=128 (48 self + 48 neigh, padded), LDS-free GEMM
    gemm_nolds<128><<<ggrid1, 256, 0, stream>>>(bufA, wt2, out2, Nn);
    agg_out8_k<<<aggGrid, 256, 0, stream>>>(out2, rowptr, cols, invd, b2, (float*)d_out, Nn);
}

// Round 11
// 449.451 us; speedup vs baseline: 1.0719x; 1.0719x over previous
//
#include <hip/hip_runtime.h>

typedef unsigned int u32;
typedef unsigned short u16;
typedef __attribute__((ext_vector_type(8))) short short8;   // 8 x bf16 (guide-verified frag type)
typedef __attribute__((ext_vector_type(4))) float f32x4;

__device__ __forceinline__ u16 f2bf(float f) {
    u32 u = __float_as_uint(f);
    u32 r = (u + 0x7fffu + ((u >> 16) & 1u)) >> 16;   // RNE
    return (u16)r;
}
__device__ __forceinline__ float bf2f(u32 lo16) { return __uint_as_float(lo16 << 16); }

__device__ __forceinline__ void acc_u4(float* a, uint4 v) {
    a[0] += bf2f(v.x & 0xffffu); a[1] += bf2f(v.x >> 16);
    a[2] += bf2f(v.y & 0xffffu); a[3] += bf2f(v.y >> 16);
    a[4] += bf2f(v.z & 0xffffu); a[5] += bf2f(v.z >> 16);
    a[6] += bf2f(v.w & 0xffffu); a[7] += bf2f(v.w >> 16);
}

// ---------------- prep ----------------

// fused transposed weights for all 3 layers in one launch
__global__ __launch_bounds__(256) void prep_w_all(const float* __restrict__ ws0, const float* __restrict__ wn0, u16* __restrict__ wt0,
                                                  const float* __restrict__ ws1, const float* __restrict__ wn1, u16* __restrict__ wt1,
                                                  const float* __restrict__ ws2, const float* __restrict__ wn2, u16* __restrict__ wt2) {
    int bid = blockIdx.x;
    const float *ws, *wn;
    u16* wt;
    int dout, HW, local;
    if (bid < 128)      { ws = ws0; wn = wn0; wt = wt0; dout = 128; HW = 128; local = bid; }
    else if (bid < 256) { ws = ws1; wn = wn1; wt = wt1; dout = 128; HW = 128; local = bid - 128; }
    else                { ws = ws2; wn = wn2; wt = wt2; dout = 47;  HW = 64;  local = bid - 256; }
    int idx = local * 256 + threadIdx.x;   // idx = n*128 + k
    int n = idx >> 7, k = idx & 127;
    float v = 0.f;
    if (n < HW) { if (n < dout) v = ws[k * dout + n]; }
    else { int nn = n - HW; if (nn < dout) v = wn[k * dout + nn]; }
    wt[idx] = f2bf(v);
}

// ---------------- CSR build ----------------

__global__ __launch_bounds__(256) void hist_k(const int* __restrict__ dst,
                                              int* __restrict__ deg, int E) {
    int i = blockIdx.x * 256 + threadIdx.x;
    if (i < E) atomicAdd(&deg[dst[i]], 1);
}

__global__ __launch_bounds__(256) void scan_partial(const int* __restrict__ deg,
                                                    int* __restrict__ bsum, int Nn) {
    __shared__ int sm[256];
    int t = threadIdx.x;
    int base = blockIdx.x * 1024 + t * 4;
    int s = 0;
#pragma unroll
    for (int j = 0; j < 4; j++)
        if (base + j < Nn) s += deg[base + j];
    sm[t] = s;
    __syncthreads();
    for (int off = 128; off > 0; off >>= 1) {
        if (t < off) sm[t] += sm[t + off];
        __syncthreads();
    }
    if (t == 0) bsum[blockIdx.x] = sm[0];
}

__global__ __launch_bounds__(256) void scan_offsets(const int* __restrict__ bsum,
                                                    int* __restrict__ boff, int nb) {
    __shared__ int sm[256];
    int t = threadIdx.x;
    int v = (t < nb) ? bsum[t] : 0;
    sm[t] = v;
    __syncthreads();
    for (int off = 1; off < 256; off <<= 1) {
        int u = (t >= off) ? sm[t - off] : 0;
        __syncthreads();
        sm[t] += u;
        __syncthreads();
    }
    if (t < nb) boff[t] = sm[t] - v;
}

// rowptr + invd + bucket cursor init (cursor[b] = rowptr[b*512])
__global__ __launch_bounds__(1024) void scan_final(const int* __restrict__ deg,
                                                   const int* __restrict__ boff,
                                                   int* __restrict__ rowptr,
                                                   float* __restrict__ invd,
                                                   int* __restrict__ cursor,
                                                   int Nn, int E) {
    __shared__ int sm[1024];
    int t = threadIdx.x;
    int i = blockIdx.x * 1024 + t;
    int v = (i < Nn) ? deg[i] : 0;
    sm[t] = v;
    __syncthreads();
    for (int off = 1; off < 1024; off <<= 1) {
        int u = (t >= off) ? sm[t - off] : 0;
        __syncthreads();
        sm[t] += u;
        __syncthreads();
    }
    if (i < Nn) {
        int rp = boff[blockIdx.x] + sm[t] - v;   // exclusive
        rowptr[i] = rp;
        invd[i] = 1.0f / (float)max(v, 1);
        if ((i & 511) == 0) cursor[i >> 9] = rp;
    }
    if (i == Nn) rowptr[Nn] = E;
}

// multisplit pass 1: tile -> LDS bucket-compaction -> contiguous bucket segments
#define TILE 4096
__global__ __launch_bounds__(512) void bucket_scatter(const int* __restrict__ src,
                                                      const int* __restrict__ dst,
                                                      int* __restrict__ cursor,
                                                      uint2* __restrict__ pairs, int E) {
    __shared__ uint2 sp[TILE];                         // 32 KB
    __shared__ int s_cnt[256], s_off[256], s_gpos[256], s_cnt2[256];
    const int tid = threadIdx.x;
    const int base = blockIdx.x * TILE;
    const int tn = min(TILE, E - base);
    if (tid < 256) { s_cnt[tid] = 0; s_cnt2[tid] = 0; }
    __syncthreads();
    int d[8], s[8];
#pragma unroll
    for (int j = 0; j < 8; j++) {
        int k = tid + j * 512;
        if (k < tn) {
            d[j] = dst[base + k];
            s[j] = src[base + k];
            atomicAdd(&s_cnt[d[j] >> 9], 1);
        } else d[j] = -1;
    }
    __syncthreads();
    if (tid < 256) s_off[tid] = s_cnt[tid];
    __syncthreads();
    for (int off = 1; off < 256; off <<= 1) {
        int v = 0;
        if (tid < 256 && tid >= off) v = s_off[tid - off];
        __syncthreads();
        if (tid < 256) s_off[tid] += v;
        __syncthreads();
    }
    if (tid < 256 && s_cnt[tid] > 0) s_gpos[tid] = atomicAdd(&cursor[tid], s_cnt[tid]);
    __syncthreads();
#pragma unroll
    for (int j = 0; j < 8; j++) {
        if (d[j] >= 0) {
            int b = d[j] >> 9;
            int p = atomicAdd(&s_cnt2[b], 1);
            sp[s_off[b] - s_cnt[b] + p] = make_uint2((u32)d[j], (u32)s[j]);
        }
    }
    __syncthreads();
    for (int k = tid; k < tn; k += 512) {
        uint2 pr = sp[k];
        int b = (int)(pr.x >> 9);
        pairs[s_gpos[b] + (k - (s_off[b] - s_cnt[b]))] = pr;
    }
}

// multisplit pass 2: per-bucket exact CSR placement via LDS counters, coalesced writeback
#define LDSCAP 12288
__global__ __launch_bounds__(512) void build_csr(const uint2* __restrict__ pairs,
                                                 const int* __restrict__ rowptr,
                                                 int* __restrict__ cols, int Nn) {
    __shared__ int s_cols[LDSCAP];                     // 48 KB
    __shared__ int s_row[513];
    __shared__ int s_cnt[512];
    const int tid = threadIdx.x;
    const int d0 = blockIdx.x * 512;
    const int nd = min(512, Nn - d0);
    for (int i = tid; i <= nd; i += 512) s_row[i] = rowptr[d0 + i];
    if (tid < nd) s_cnt[tid] = 0;
    __syncthreads();
    const int base = s_row[0];
    const int n = s_row[nd] - base;
    const bool fit = (n <= LDSCAP);
    for (int k = tid; k < n; k += 512) {
        uint2 pr = pairs[base + k];
        int dl = (int)pr.x - d0;
        int p = atomicAdd(&s_cnt[dl], 1);
        int pos = s_row[dl] - base + p;
        if (fit) s_cols[pos] = (int)pr.y;
        else cols[base + pos] = (int)pr.y;             // overflow fallback (never expected)
    }
    __syncthreads();
    if (fit)
        for (int k = tid; k < n; k += 512) cols[base + k] = s_cols[k];
}

// ---------------- fused GEMM: C[M][NCOLS] = A[M][128] @ Bt^T  (fp32 acc) ----------------
// AF32: A is fp32 (layer 0 reads x directly, converts during LDS staging).
// Epilogue: acc -> LDS (As reused) -> coalesced uint4 stores (16 B/lane).
#define KDIM 128
#define KP 136

template <int NCOLS, bool AF32>
__global__ __launch_bounds__(256) void gemm_bf16(const void* __restrict__ Ap,
                                                 const u16* __restrict__ Bt,
                                                 u16* __restrict__ C, int M) {
    __shared__ u16 As[64 * KP];
    __shared__ u16 Bs[128 * KP];
    const int row0 = blockIdx.x * 64;
    const int col0 = blockIdx.y * 128;
    const int tid = threadIdx.x;

#pragma unroll
    for (int i = 0; i < 4; i++) {
        int idx = tid + i * 256;
        int r = idx >> 4, c = idx & 15;
        uint4 v = make_uint4(0, 0, 0, 0);
        if (row0 + r < M) {
            if (AF32) {
                const float* Af = (const float*)Ap;
                const float4* rowp = (const float4*)(Af + (size_t)(row0 + r) * KDIM);
                float4 f0 = rowp[2 * c];
                float4 f1 = rowp[2 * c + 1];
                v.x = (u32)f2bf(f0.x) | ((u32)f2bf(f0.y) << 16);
                v.y = (u32)f2bf(f0.z) | ((u32)f2bf(f0.w) << 16);
                v.z = (u32)f2bf(f1.x) | ((u32)f2bf(f1.y) << 16);
                v.w = (u32)f2bf(f1.z) | ((u32)f2bf(f1.w) << 16);
            } else {
                const u16* Ab = (const u16*)Ap;
                v = ((const uint4*)(Ab + (size_t)(row0 + r) * KDIM))[c];
            }
        }
        ((uint4*)(As + r * KP))[c] = v;
    }
#pragma unroll
    for (int i = 0; i < 8; i++) {
        int idx = tid + i * 256;
        int r = idx >> 4, c = idx & 15;
        uint4 v = ((const uint4*)(Bt + (size_t)(col0 + r) * KDIM))[c];
        ((uint4*)(Bs + r * KP))[c] = v;
    }
    __syncthreads();

    const int lane = tid & 63, wave = tid >> 6;
    const int quad = lane >> 4, l16 = lane & 15;
    const int wcol = wave * 32;

    f32x4 acc[4][2];
#pragma unroll
    for (int mt = 0; mt < 4; mt++)
#pragma unroll
        for (int nt = 0; nt < 2; nt++) acc[mt][nt] = (f32x4){0.f, 0.f, 0.f, 0.f};

#pragma unroll
    for (int kc = 0; kc < 4; kc++) {
        short8 a[4], b[2];
#pragma unroll
        for (int mt = 0; mt < 4; mt++)
            a[mt] = *(const short8*)(As + (size_t)(mt * 16 + l16) * KP + kc * 32 + quad * 8);
#pragma unroll
        for (int nt = 0; nt < 2; nt++)
            b[nt] = *(const short8*)(Bs + (size_t)(wcol + nt * 16 + l16) * KP + kc * 32 + quad * 8);
#pragma unroll
        for (int mt = 0; mt < 4; mt++)
#pragma unroll
            for (int nt = 0; nt < 2; nt++)
                acc[mt][nt] = __builtin_amdgcn_mfma_f32_16x16x32_bf16(a[mt], b[nt], acc[mt][nt], 0, 0, 0);
    }

    // Epilogue: C/D layout col=lane&15, row=quad*4+reg [verified m89/m91].
    // Scalar 2B stores scatter badly -> round-trip through As (dead after MFMAs)
    // and store coalesced 16 B/lane.
    __syncthreads();                                    // all waves done reading As/Bs
#pragma unroll
    for (int mt = 0; mt < 4; mt++)
#pragma unroll
        for (int i = 0; i < 4; i++) {
            int rl = mt * 16 + quad * 4 + i;
#pragma unroll
            for (int nt = 0; nt < 2; nt++)
                As[rl * KP + wcol + nt * 16 + l16] = f2bf(acc[mt][nt][i]);
        }
    __syncthreads();
#pragma unroll
    for (int it = 0; it < 4; it++) {
        int idx = tid + it * 256;
        int r = idx >> 4, c8 = idx & 15;                // 16 x uint4 per 128-col row
        if (row0 + r < M)
            *(uint4*)(C + (size_t)(row0 + r) * NCOLS + col0 + c8 * 8) =
                *(const uint4*)(As + r * KP + c8 * 8);
    }
}

// ---------------- 128-col aggregation: 2 nodes/wave, 4 gathers in flight ----------------
// out2 = [M][256] bf16 (s | t).  outp = [M][128] bf16.
template <bool RELU>
__global__ __launch_bounds__(256) void agg128_k(const u16* __restrict__ out2,
                                                const int* __restrict__ rowptr,
                                                const int* __restrict__ cols,
                                                const float* __restrict__ invd,
                                                const float* __restrict__ bias,
                                                u16* __restrict__ outp, int Mn) {
    int wave = threadIdx.x >> 6, lane = threadIdx.x & 63;
    int nA = blockIdx.x * 8 + wave * 2;
    if (nA >= Mn) return;
    const int nB = nA + 1;
    const bool hasB = (nB < Mn);
    int sub = lane >> 4, l16 = lane & 15;               // 4 slots x 16 lanes
    const u16* tb = out2 + 128 + 8 * l16;
    int begA = rowptr[nA], endA = rowptr[nA + 1];
    int begB = 0, endB = 0;
    if (hasB) { begB = rowptr[nB]; endB = rowptr[nB + 1]; }
    float aA[8] = {0.f, 0.f, 0.f, 0.f, 0.f, 0.f, 0.f, 0.f};
    float aB[8] = {0.f, 0.f, 0.f, 0.f, 0.f, 0.f, 0.f, 0.f};
    int eA = begA + sub, eB = begB + sub;
    while (eA < endA || eB < endB) {
        bool pA0 = eA < endA, pA1 = eA + 4 < endA;
        bool pB0 = eB < endB, pB1 = eB + 4 < endB;
        int sA0 = pA0 ? cols[eA] : 0;
        int sA1 = pA1 ? cols[eA + 4] : 0;
        int sB0 = pB0 ? cols[eB] : 0;
        int sB1 = pB1 ? cols[eB + 4] : 0;
        uint4 vA0 = *(const uint4*)(tb + (size_t)sA0 * 256);
        uint4 vA1 = *(const uint4*)(tb + (size_t)sA1 * 256);
        uint4 vB0 = *(const uint4*)(tb + (size_t)sB0 * 256);
        uint4 vB1 = *(const uint4*)(tb + (size_t)sB1 * 256);
        if (!pA0) vA0 = make_uint4(0, 0, 0, 0);
        if (!pA1) vA1 = make_uint4(0, 0, 0, 0);
        if (!pB0) vB0 = make_uint4(0, 0, 0, 0);
        if (!pB1) vB1 = make_uint4(0, 0, 0, 0);
        acc_u4(aA, vA0); acc_u4(aA, vA1);
        acc_u4(aB, vB0); acc_u4(aB, vB1);
        eA += 8; eB += 8;
    }
#pragma unroll
    for (int j = 0; j < 8; j++) {                       // reduce across 4 slots
        aA[j] += __shfl_xor(aA[j], 16); aA[j] += __shfl_xor(aA[j], 32);
        aB[j] += __shfl_xor(aB[j], 16); aB[j] += __shfl_xor(aB[j], 32);
    }
    if (sub == 0 || (sub == 1 && hasB)) {               // sub0 -> nA, sub1 -> nB (parallel epilogues)
        int node = (sub == 0) ? nA : nB;
        float o[8];
#pragma unroll
        for (int j = 0; j < 8; j++) o[j] = (sub == 0) ? aA[j] : aB[j];
        float id = invd[node];
        uint4 sv = *(const uint4*)(out2 + (size_t)node * 256 + 8 * l16);
        float4 b0 = *(const float4*)(bias + 8 * l16);
        float4 b1 = *(const float4*)(bias + 8 * l16 + 4);
        float o0 = bf2f(sv.x & 0xffffu) + o[0] * id + b0.x;
        float o1 = bf2f(sv.x >> 16)     + o[1] * id + b0.y;
        float o2 = bf2f(sv.y & 0xffffu) + o[2] * id + b0.z;
        float o3 = bf2f(sv.y >> 16)     + o[3] * id + b0.w;
        float o4 = bf2f(sv.z & 0xffffu) + o[4] * id + b1.x;
        float o5 = bf2f(sv.z >> 16)     + o[5] * id + b1.y;
        float o6 = bf2f(sv.w & 0xffffu) + o[6] * id + b1.z;
        float o7 = bf2f(sv.w >> 16)     + o[7] * id + b1.w;
        if (RELU) {
            o0 = fmaxf(o0, 0.f); o1 = fmaxf(o1, 0.f); o2 = fmaxf(o2, 0.f); o3 = fmaxf(o3, 0.f);
            o4 = fmaxf(o4, 0.f); o5 = fmaxf(o5, 0.f); o6 = fmaxf(o6, 0.f); o7 = fmaxf(o7, 0.f);
        }
        uint4 w;
        w.x = (u32)f2bf(o0) | ((u32)f2bf(o1) << 16);
        w.y = (u32)f2bf(o2) | ((u32)f2bf(o3) << 16);
        w.z = (u32)f2bf(o4) | ((u32)f2bf(o5) << 16);
        w.w = (u32)f2bf(o6) | ((u32)f2bf(o7) << 16);
        *(uint4*)(outp + (size_t)node * 128 + 8 * l16) = w;
    }
}

// ---------------- layer-2 aggregation: 2 nodes/wave, 4 gathers in flight, fp32 out ----------------
// out2 = [M][128] bf16: s at cols 0..63 (live 0..46), t at cols 64..127 (live 64..110).
__global__ __launch_bounds__(256) void agg_out8_k(const u16* __restrict__ out2,
                                                  const int* __restrict__ rowptr,
                                                  const int* __restrict__ cols,
                                                  const float* __restrict__ invd,
                                                  const float* __restrict__ bias,
                                                  float* __restrict__ outp, int Mn) {
    int wave = threadIdx.x >> 6, lane = threadIdx.x & 63;
    int nA = blockIdx.x * 8 + wave * 2;
    if (nA >= Mn) return;
    const int nB = nA + 1;
    const bool hasB = (nB < Mn);
    int e8 = lane >> 3, l8 = lane & 7;                  // 8 slots x 8 lanes
    const u16* tb = out2 + 64 + 8 * l8;
    int begA = rowptr[nA], endA = rowptr[nA + 1];
    int begB = 0, endB = 0;
    if (hasB) { begB = rowptr[nB]; endB = rowptr[nB + 1]; }
    float aA[8] = {0.f, 0.f, 0.f, 0.f, 0.f, 0.f, 0.f, 0.f};
    float aB[8] = {0.f, 0.f, 0.f, 0.f, 0.f, 0.f, 0.f, 0.f};
    int eA = begA + e8, eB = begB + e8;
    while (eA < endA || eB < endB) {
        bool pA0 = eA < endA, pA1 = eA + 8 < endA;
        bool pB0 = eB < endB, pB1 = eB + 8 < endB;
        int sA0 = pA0 ? cols[eA] : 0;
        int sA1 = pA1 ? cols[eA + 8] : 0;
        int sB0 = pB0 ? cols[eB] : 0;
        int sB1 = pB1 ? cols[eB + 8] : 0;
        uint4 vA0 = *(const uint4*)(tb + (size_t)sA0 * 128);
        uint4 vA1 = *(const uint4*)(tb + (size_t)sA1 * 128);
        uint4 vB0 = *(const uint4*)(tb + (size_t)sB0 * 128);
        uint4 vB1 = *(const uint4*)(tb + (size_t)sB1 * 128);
        if (!pA0) vA0 = make_uint4(0, 0, 0, 0);
        if (!pA1) vA1 = make_uint4(0, 0, 0, 0);
        if (!pB0) vB0 = make_uint4(0, 0, 0, 0);
        if (!pB1) vB1 = make_uint4(0, 0, 0, 0);
        acc_u4(aA, vA0); acc_u4(aA, vA1);
        acc_u4(aB, vB0); acc_u4(aB, vB1);
        eA += 16; eB += 16;
    }
#pragma unroll
    for (int j = 0; j < 8; j++) {                       // reduce across 8 slots
        aA[j] += __shfl_xor(aA[j], 8); aA[j] += __shfl_xor(aA[j], 16); aA[j] += __shfl_xor(aA[j], 32);
        aB[j] += __shfl_xor(aB[j], 8); aB[j] += __shfl_xor(aB[j], 16); aB[j] += __shfl_xor(aB[j], 32);
    }
    if (e8 == 0 || (e8 == 1 && hasB)) {                 // e8==0 -> nA, e8==1 -> nB
        int node = (e8 == 0) ? nA : nB;
        float o[8];
#pragma unroll
        for (int j = 0; j < 8; j++) o[j] = (e8 == 0) ? aA[j] : aB[j];
        float id = invd[node];
        uint4 sv = *(const uint4*)(out2 + (size_t)node * 128 + 8 * l8);
        u32 sw[4] = {sv.x, sv.y, sv.z, sv.w};
        float* orow = outp + (size_t)node * 47;
#pragma unroll
        for (int j = 0; j < 8; j++) {
            int c = 8 * l8 + j;
            if (c < 47) {
                float s = bf2f((j & 1) ? (sw[j >> 1] >> 16) : (sw[j >> 1] & 0xffffu));
                orow[c] = s + o[j] * id + bias[c];
            }
        }
    }
}

// ---------------- launch ----------------

extern "C" void kernel_launch(void* const* d_in, const int* in_sizes, int n_in,
                              void* d_out, int out_size, void* d_ws, size_t ws_size,
                              hipStream_t stream) {
    const float* x   = (const float*)d_in[0];
    const int*   src = (const int*)d_in[1];
    const int*   dst = (const int*)d_in[2];
    const float* ws0 = (const float*)d_in[3];
    const float* wn0 = (const float*)d_in[4];
    const float* b0  = (const float*)d_in[5];
    const float* ws1 = (const float*)d_in[6];
    const float* wn1 = (const float*)d_in[7];
    const float* b1  = (const float*)d_in[8];
    const float* ws2 = (const float*)d_in[9];
    const float* wn2 = (const float*)d_in[10];
    const float* b2  = (const float*)d_in[11];

    const int Nn = in_sizes[0] / 128;   // 100000
    const int E  = in_sizes[1];         // 1600000

    char* p = (char*)d_ws;
    auto alloc = [&](size_t bytes) -> void* {
        void* r = (void*)p;
        p += (bytes + 255) & ~(size_t)255;
        return r;
    };
    u16*   bufA   = (u16*)alloc((size_t)Nn * 128 * 2);   // h1 / h2
    u16*   out2   = (u16*)alloc((size_t)Nn * 256 * 2);   // [s|t] per layer; ALSO overlaid as pairs buf
    u16*   wt0    = (u16*)alloc(256 * 128 * 2);
    u16*   wt1    = (u16*)alloc(256 * 128 * 2);
    u16*   wt2    = (u16*)alloc(128 * 128 * 2);
    int*   deg    = (int*)alloc((size_t)Nn * 4);
    int*   rowptr = (int*)alloc((size_t)(Nn + 1) * 4);
    float* invd   = (float*)alloc((size_t)Nn * 4);
    int*   cols   = (int*)alloc((size_t)E * 4);
    int*   bsum   = (int*)alloc(256 * 4);
    int*   boff   = (int*)alloc(256 * 4);
    int*   cursor = (int*)alloc(256 * 4);
    uint2* pairs  = (uint2*)out2;                        // overlay: out2 unused until gemm layer 0

    hipMemsetAsync(deg, 0, (size_t)Nn * 4, stream);

    prep_w_all<<<320, 256, 0, stream>>>(ws0, wn0, wt0, ws1, wn1, wt1, ws2, wn2, wt2);

    hist_k<<<(E + 255) / 256, 256, 0, stream>>>(dst, deg, E);
    const int nb = (Nn + 1023) / 1024;
    const int nb2 = (Nn + 1 + 1023) / 1024;
    scan_partial<<<nb, 256, 0, stream>>>(deg, bsum, Nn);
    scan_offsets<<<1, 256, 0, stream>>>(bsum, boff, nb);
    scan_final<<<nb2, 1024, 0, stream>>>(deg, boff, rowptr, invd, cursor, Nn, E);

    bucket_scatter<<<(E + TILE - 1) / TILE, 512, 0, stream>>>(src, dst, cursor, pairs, E);
    build_csr<<<(Nn + 511) / 512, 512, 0, stream>>>(pairs, rowptr, cols, Nn);

    dim3 ggrid((Nn + 63) / 64, 2);
    dim3 ggrid1((Nn + 63) / 64, 1);
    const int aggGrid = (Nn + 7) / 8;                    // 4 waves x 2 nodes = 8 nodes/block
    // layer 0: LDS-staged GEMM reads x fp32 directly (cvt fused into staging)
    gemm_bf16<256, true><<<ggrid, 256, 0, stream>>>(x, wt0, out2, Nn);
    agg128_k<true><<<aggGrid, 256, 0, stream>>>(out2, rowptr, cols, invd, b0, bufA, Nn);
    // layer 1
    gemm_bf16<256, false><<<ggrid, 256, 0, stream>>>(bufA, wt1, out2, Nn);
    agg128_k<true><<<aggGrid, 256, 0, stream>>>(out2, rowptr, cols, invd, b1, bufA, Nn);
    // layer 2: N=128 (48 self + 48 neigh, padded)
    gemm_bf16<128, false><<<ggrid1, 256, 0, stream>>>(bufA, wt2, out2, Nn);
    agg_out8_k<<<aggGrid, 256, 0, stream>>>(out2, rowptr, cols, invd, b2, (float*)d_out, Nn);
}